// Round 1
// baseline (626.777 us; speedup 1.0000x reference)
//
#include <hip/hip_runtime.h>

typedef _Float16 f16;
typedef _Float16 f16x8 __attribute__((ext_vector_type(8)));
typedef float    f32x4 __attribute__((ext_vector_type(4)));

#define BSZ 4
#define SL  2048
#define NK  24
#define DD  512
#define VCOPY 2176   // halfs per shifted copy of vrev

typedef const void GV __attribute__((address_space(1)));
typedef void       LV __attribute__((address_space(3)));

__device__ __forceinline__ void gload_lds16(const void* gp, void* lp) {
  // dest = lp (wave-uniform) + lane*16
  __builtin_amdgcn_global_load_lds((GV*)gp, (LV*)lp, 16, 0, 0);
}

// ---------------- prep: vrev8[i][c][j] = val(j+c), val(p)= p<2048 ? v[2047-p,i]*lam_i^0.25 : 0
__global__ void k_vrev8(const float* __restrict__ eig_vals,
                        const float* __restrict__ eig_vecs,
                        f16* __restrict__ vrev8) {
  int i = blockIdx.x, c = blockIdx.y;
  float sc = sqrtf(sqrtf(eig_vals[i]));
  f16* dst = vrev8 + ((size_t)i * 8 + c) * VCOPY;
  for (int j = threadIdx.x; j < VCOPY; j += 256) {
    int p = j + c;
    float v = (p < SL) ? eig_vecs[(size_t)(SL - 1 - p) * NK + i] * sc : 0.f;
    dst[j] = (f16)v;
  }
}

// ---------------- prep: ut[b][d][s] = (f16) u[b][s][d]
__global__ void k_tu(const float* __restrict__ u, f16* __restrict__ ut) {
  __shared__ float tile[32][33];
  int b = blockIdx.z;
  int s0 = blockIdx.x * 32, d0 = blockIdx.y * 32;
  int tx = threadIdx.x, ty = threadIdx.y;
#pragma unroll
  for (int r = 0; r < 4; ++r) {
    int s = s0 + ty * 4 + r;
    tile[ty * 4 + r][tx] = u[((size_t)b * SL + s) * DD + d0 + tx];
  }
  __syncthreads();
#pragma unroll
  for (int r = 0; r < 4; ++r) {
    int d = d0 + ty * 4 + r;
    ut[((size_t)b * DD + d) * SL + s0 + tx] = (f16)tile[tx][ty * 4 + r];
  }
}

// ---------------- prep: mht[e][k] = (f16) m_phi[k][e]   (B^T layout)
__global__ void k_tm(const float* __restrict__ mp, f16* __restrict__ mht) {
  __shared__ float tile[32][33];
  int k0 = blockIdx.x * 32, e0 = blockIdx.y * 32;
  int tx = threadIdx.x, ty = threadIdx.y;
#pragma unroll
  for (int r = 0; r < 4; ++r)
    tile[ty * 4 + r][tx] = mp[(size_t)(k0 + ty * 4 + r) * DD + e0 + tx];
  __syncthreads();
#pragma unroll
  for (int r = 0; r < 4; ++r)
    mht[(size_t)(e0 + ty * 4 + r) * (NK * DD) + k0 + tx] = (f16)tile[tx][ty * 4 + r];
}

// ---------------- phase A: causal Toeplitz conv -> xt[b][t][iL*512+d] (fp16)
// grid: x = 32 (tb 16 x dhalf 2), y = KI, z = b ; 256 threads (4 waves), wave tile 128t x 64d
__global__ __launch_bounds__(256, 2) void k_conv(
    const f16* __restrict__ ut, const f16* __restrict__ vrev8,
    f16* __restrict__ xt, int KI, int ibase) {
  __shared__ f16 vl[8 * VCOPY];   // 34,816 B
  __shared__ f16 bt[256 * 32];    // 16,384 B
  const int tid = threadIdx.x;
  const int tb = 15 - (blockIdx.x >> 1);   // reversed: big K-loops first
  const int dh = blockIdx.x & 1;
  const int iL = blockIdx.y;
  const int i  = ibase + iL;
  const int b  = blockIdx.z;
  const int t0 = tb * 128;

  { // stage all 8 shifted copies of vrev (linear 16B copy)
    const uint4* src = (const uint4*)(vrev8 + (size_t)i * (8 * VCOPY));
    uint4* dst = (uint4*)vl;
    for (int p = tid; p < (8 * VCOPY) / 8; p += 256) dst[p] = src[p];
  }

  const int w = tid >> 6, l = tid & 63;
  const int l15 = l & 15, lq = l >> 4, k8 = lq << 3;

  f32x4 acc[8][4];
#pragma unroll
  for (int m = 0; m < 8; ++m)
#pragma unroll
    for (int n = 0; n < 4; ++n) acc[m][n] = (f32x4){0.f, 0.f, 0.f, 0.f};

  const f16* utb = ut + (size_t)b * DD * SL;

  for (int s0 = 0; s0 < t0 + 128; s0 += 32) {
    __syncthreads();
    // stage bt[256][32] <- ut[b][dh*256 + r][s0..s0+32)
#pragma unroll
    for (int j = 0; j < 4; ++j) {
      int row = w * 64 + j * 16 + (l >> 2);
      const f16* g = utb + (size_t)(dh * 256 + row) * SL + s0 + (l & 3) * 8;
      gload_lds16(g, bt + (w * 64 + j * 16) * 32);
    }
    __syncthreads();

    f16x8 B[4];
#pragma unroll
    for (int n = 0; n < 4; ++n)
      B[n] = *(const f16x8*)(bt + (w * 64 + n * 16 + l15) * 32 + k8);

    const int cbase = 2047 - t0 + s0 + k8;
#pragma unroll
    for (int m = 0; m < 8; ++m) {
      int idx = cbase - (m * 16 + l15);     // vrev index of k-slot j=0 (ascending in j)
      int c = idx & 7, a = idx & ~7;
      f16x8 A = *(const f16x8*)(vl + c * VCOPY + a);
#pragma unroll
      for (int n = 0; n < 4; ++n)
        acc[m][n] = __builtin_amdgcn_mfma_f32_16x16x32_f16(A, B[n], acc[m][n], 0, 0, 0);
    }
  }

  // store xt fp16: D frag: col=lane&15 (d), row=(lane>>4)*4+r (t)
  const size_t rowlen = (size_t)KI * DD;
  const int dbase = dh * 256 + w * 64;
#pragma unroll
  for (int m = 0; m < 8; ++m) {
    int t = t0 + m * 16 + lq * 4;
#pragma unroll
    for (int n = 0; n < 4; ++n) {
      int d = dbase + n * 16 + l15;
      f16* dst = xt + ((size_t)(b * SL + t) * KI + iL) * DD + d;
#pragma unroll
      for (int r = 0; r < 4; ++r)
        dst[(size_t)r * rowlen] = (f16)acc[m][n][r];
    }
  }
}

// ---------------- phase B: out[8192][512] (+)= xt[8192][KI*512] @ mht^T
// BM=64, BN=128, BK=64; grid (4, 128); 256 thr, 4 waves (2m x 2n), wave 32x64
__global__ __launch_bounds__(256) void k_gemm(
    const f16* __restrict__ xt, const f16* __restrict__ mht,
    float* __restrict__ out, int KI, int kc0, int beta) {
  __shared__ f16 at[64 * 64];     // 8 KB
  __shared__ f16 btl[128 * 64];   // 16 KB
  const int tid = threadIdx.x;
  const int n0 = blockIdx.x * 128;
  const int m0 = blockIdx.y * 64;
  const int w = tid >> 6, l = tid & 63;
  const int l15 = l & 15, lq = l >> 4, k8 = lq << 3;
  const int wm = w >> 1, wn = w & 1;
  const int KLEN = KI * DD;

  f32x4 acc[2][4];
#pragma unroll
  for (int m = 0; m < 2; ++m)
#pragma unroll
    for (int n = 0; n < 4; ++n) acc[m][n] = (f32x4){0.f, 0.f, 0.f, 0.f};

  for (int k0 = 0; k0 < KLEN; k0 += 64) {
    __syncthreads();
#pragma unroll
    for (int j = 0; j < 2; ++j) {  // A tile [64][64]
      int row = (w * 2 + j) * 8 + (l >> 3);
      const f16* g = xt + (size_t)(m0 + row) * KLEN + k0 + (l & 7) * 8;
      gload_lds16(g, at + (w * 2 + j) * 8 * 64);
    }
#pragma unroll
    for (int j = 0; j < 4; ++j) {  // B tile [128][64]
      int row = (w * 4 + j) * 8 + (l >> 3);
      const f16* g = mht + (size_t)(n0 + row) * (NK * DD) + kc0 + k0 + (l & 7) * 8;
      gload_lds16(g, btl + (w * 4 + j) * 8 * 64);
    }
    __syncthreads();
#pragma unroll
    for (int ks = 0; ks < 2; ++ks) {
      f16x8 Bf[4];
#pragma unroll
      for (int n = 0; n < 4; ++n)
        Bf[n] = *(const f16x8*)(btl + (wn * 64 + n * 16 + l15) * 64 + ks * 32 + k8);
#pragma unroll
      for (int m = 0; m < 2; ++m) {
        f16x8 Af = *(const f16x8*)(at + (wm * 32 + m * 16 + l15) * 64 + ks * 32 + k8);
#pragma unroll
        for (int n = 0; n < 4; ++n)
          acc[m][n] = __builtin_amdgcn_mfma_f32_16x16x32_f16(Af, Bf[n], acc[m][n], 0, 0, 0);
      }
    }
  }

#pragma unroll
  for (int m = 0; m < 2; ++m) {
    int row = m0 + wm * 32 + m * 16 + lq * 4;
#pragma unroll
    for (int n = 0; n < 4; ++n) {
      int e = n0 + wn * 64 + n * 16 + l15;
      float* dst = out + (size_t)row * DD + e;
#pragma unroll
      for (int r = 0; r < 4; ++r) {
        float v = acc[m][n][r];
        if (beta) v += dst[(size_t)r * DD];
        dst[(size_t)r * DD] = v;
      }
    }
  }
}

extern "C" void kernel_launch(void* const* d_in, const int* in_sizes, int n_in,
                              void* d_out, int out_size, void* d_ws, size_t ws_size,
                              hipStream_t stream) {
  const float* u    = (const float*)d_in[0];  // [4,2048,512]
  const float* ev   = (const float*)d_in[1];  // [24]
  const float* evec = (const float*)d_in[2];  // [2048,24]
  const float* mp   = (const float*)d_in[3];  // [12288,512]
  float* out = (float*)d_out;
  char* ws = (char*)d_ws;

  const size_t UT_OFF   = 0;                       // 8,388,608 B
  const size_t MHT_OFF  = 8388608;                 // 12,582,912 B
  const size_t VREV_OFF = 20971520;                // 24*8*2176*2 = 835,584 B
  const size_t XT_OFF   = 21807104;

  f16* ut    = (f16*)(ws + UT_OFF);
  f16* mht   = (f16*)(ws + MHT_OFF);
  f16* vrev8 = (f16*)(ws + VREV_OFF);
  f16* xt    = (f16*)(ws + XT_OFF);

  // pick largest i-chunk that fits the workspace
  int KI = 1;
  const int cands[8] = {24, 12, 8, 6, 4, 3, 2, 1};
  for (int ci = 0; ci < 8; ++ci) {
    size_t need = XT_OFF + (size_t)cands[ci] * 8388608ull;
    if (need <= ws_size) { KI = cands[ci]; break; }
  }
  const int NC = NK / KI;

  k_vrev8<<<dim3(24, 8), 256, 0, stream>>>(ev, evec, vrev8);
  k_tu<<<dim3(SL / 32, DD / 32, BSZ), dim3(32, 8), 0, stream>>>(u, ut);
  k_tm<<<dim3((NK * DD) / 32, DD / 32), dim3(32, 8), 0, stream>>>(mp, mht);

  for (int c = 0; c < NC; ++c) {
    k_conv<<<dim3(32, KI, BSZ), 256, 0, stream>>>(ut, vrev8, xt, KI, c * KI);
    k_gemm<<<dim3(DD / 128, (BSZ * SL) / 64), 256, 0, stream>>>(
        xt, mht, out, KI, c * KI * DD, c > 0);
  }
}

// Round 2
// 546.124 us; speedup vs baseline: 1.1477x; 1.1477x over previous
//
#include <hip/hip_runtime.h>

typedef _Float16 f16;
typedef _Float16 f16x8 __attribute__((ext_vector_type(8)));
typedef float    f32x4 __attribute__((ext_vector_type(4)));

#define BSZ 4
#define SL  2048
#define NK  24
#define DD  512
#define VCOPY 2184   // halfs per shifted copy; 2184*2/4=1092 dwords == 4 mod 32 -> copies spread over banks

typedef const void GV __attribute__((address_space(1)));
typedef void       LV __attribute__((address_space(3)));

__device__ __forceinline__ void gload_lds16(const void* gp, void* lp) {
  // dest = lp (wave-uniform) + lane*16
  __builtin_amdgcn_global_load_lds((GV*)gp, (LV*)lp, 16, 0, 0);
}

// ---------------- prep: vrev8[i][c][j] = val(j+c), val(p)= p<2048 ? v[2047-p,i]*lam_i^0.25 : 0
__global__ void k_vrev8(const float* __restrict__ eig_vals,
                        const float* __restrict__ eig_vecs,
                        f16* __restrict__ vrev8) {
  int i = blockIdx.x, c = blockIdx.y;
  float sc = sqrtf(sqrtf(eig_vals[i]));
  f16* dst = vrev8 + ((size_t)i * 8 + c) * VCOPY;
  for (int j = threadIdx.x; j < VCOPY; j += 256) {
    int p = j + c;
    float v = (p < SL) ? eig_vecs[(size_t)(SL - 1 - p) * NK + i] * sc : 0.f;
    dst[j] = (f16)v;
  }
}

// ---------------- prep: ut[b][d][s] = (f16) u[b][s][d]
__global__ void k_tu(const float* __restrict__ u, f16* __restrict__ ut) {
  __shared__ float tile[32][33];
  int b = blockIdx.z;
  int s0 = blockIdx.x * 32, d0 = blockIdx.y * 32;
  int tx = threadIdx.x, ty = threadIdx.y;
#pragma unroll
  for (int r = 0; r < 4; ++r) {
    int s = s0 + ty * 4 + r;
    tile[ty * 4 + r][tx] = u[((size_t)b * SL + s) * DD + d0 + tx];
  }
  __syncthreads();
#pragma unroll
  for (int r = 0; r < 4; ++r) {
    int d = d0 + ty * 4 + r;
    ut[((size_t)b * DD + d) * SL + s0 + tx] = (f16)tile[tx][ty * 4 + r];
  }
}

// ---------------- prep: mht[e][k] = (f16) m_phi[k][e]   (B^T layout)
__global__ void k_tm(const float* __restrict__ mp, f16* __restrict__ mht) {
  __shared__ float tile[32][33];
  int k0 = blockIdx.x * 32, e0 = blockIdx.y * 32;
  int tx = threadIdx.x, ty = threadIdx.y;
#pragma unroll
  for (int r = 0; r < 4; ++r)
    tile[ty * 4 + r][tx] = mp[(size_t)(k0 + ty * 4 + r) * DD + e0 + tx];
  __syncthreads();
#pragma unroll
  for (int r = 0; r < 4; ++r)
    mht[(size_t)(e0 + ty * 4 + r) * (NK * DD) + k0 + tx] = (f16)tile[tx][ty * 4 + r];
}

// ---------------- phase A: causal Toeplitz conv -> xt[b][t][iL*512+d] (fp16)
// grid: x = 32 (tb 16 x dhalf 2), y = KI, z = b ; 256 threads (4 waves), wave tile 128t x 64d
// bt swizzle: phys = lin ^ ((row&3)<<4)  (involution; spreads 64-lane b128 reads over all banks)
__global__ __launch_bounds__(256, 2) void k_conv(
    const f16* __restrict__ ut, const f16* __restrict__ vrev8,
    f16* __restrict__ xt, int KI, int ibase) {
  __shared__ f16 vl[8 * VCOPY];   // 34,944 B
  __shared__ f16 bt[256 * 32];    // 16,384 B
  const int tid = threadIdx.x;
  const int tb = 15 - (blockIdx.x >> 1);   // reversed: big K-loops first
  const int dh = blockIdx.x & 1;
  const int iL = blockIdx.y;
  const int i  = ibase + iL;
  const int b  = blockIdx.z;
  const int t0 = tb * 128;

  { // stage all 8 shifted copies of vrev (linear 16B copy)
    const uint4* src = (const uint4*)(vrev8 + (size_t)i * (8 * VCOPY));
    uint4* dst = (uint4*)vl;
    for (int p = tid; p < (8 * VCOPY) / 8; p += 256) dst[p] = src[p];
  }

  const int w = tid >> 6, l = tid & 63;
  const int l15 = l & 15, lq = l >> 4, k8 = lq << 3;
  // pre-swizzled global column for B staging (write-side of the involution)
  const int stage_col = ((l & 3) ^ ((l >> 2) & 3)) * 8;
  const int stage_row = l >> 2;

  f32x4 acc[8][4];
#pragma unroll
  for (int m = 0; m < 8; ++m)
#pragma unroll
    for (int n = 0; n < 4; ++n) acc[m][n] = (f32x4){0.f, 0.f, 0.f, 0.f};

  const f16* utb = ut + (size_t)b * DD * SL;

  for (int s0 = 0; s0 < t0 + 128; s0 += 32) {
    __syncthreads();
    // stage bt[256][32] <- ut[b][dh*256 + r][s0..s0+32), source col pre-swizzled
#pragma unroll
    for (int j = 0; j < 4; ++j) {
      int row = w * 64 + j * 16 + stage_row;
      const f16* g = utb + (size_t)(dh * 256 + row) * SL + s0 + stage_col;
      gload_lds16(g, bt + (w * 64 + j * 16) * 32);
    }
    __syncthreads();

    f16x8 B[4];
#pragma unroll
    for (int n = 0; n < 4; ++n) {
      int lin = (w * 64 + n * 16 + l15) * 64 + lq * 16;
      lin ^= (l15 & 3) << 4;
      B[n] = *(const f16x8*)((const char*)bt + lin);
    }

    const int cbase = 2047 - t0 + s0 + k8;
#pragma unroll
    for (int m = 0; m < 8; ++m) {
      int idx = cbase - (m * 16 + l15);     // vrev index of k-slot j=0 (ascending in j)
      int c = idx & 7, a = idx & ~7;
      f16x8 A = *(const f16x8*)(vl + c * VCOPY + a);
#pragma unroll
      for (int n = 0; n < 4; ++n)
        acc[m][n] = __builtin_amdgcn_mfma_f32_16x16x32_f16(A, B[n], acc[m][n], 0, 0, 0);
    }
  }

  // store xt fp16: D frag: col=lane&15 (d), row=(lane>>4)*4+r (t)
  const size_t rowlen = (size_t)KI * DD;
  const int dbase = dh * 256 + w * 64;
#pragma unroll
  for (int m = 0; m < 8; ++m) {
    int t = t0 + m * 16 + lq * 4;
#pragma unroll
    for (int n = 0; n < 4; ++n) {
      int d = dbase + n * 16 + l15;
      f16* dst = xt + ((size_t)(b * SL + t) * KI + iL) * DD + d;
#pragma unroll
      for (int r = 0; r < 4; ++r)
        dst[(size_t)r * rowlen] = (f16)acc[m][n][r];
    }
  }
}

// ---------------- phase B: out[8192][512] (+)= xt[8192][KI*512] @ mht^T
// BM=64, BN=128, BK=64; grid (4, 128); 256 thr, 4 waves (2m x 2n), wave 32x64
// at/btl swizzle: phys = lin ^ ((row&7)<<4)
__global__ __launch_bounds__(256) void k_gemm(
    const f16* __restrict__ xt, const f16* __restrict__ mht,
    float* __restrict__ out, int KI, int kc0, int beta) {
  __shared__ f16 at[64 * 64];     // 8 KB
  __shared__ f16 btl[128 * 64];   // 16 KB
  const int tid = threadIdx.x;
  const int n0 = blockIdx.x * 128;
  const int m0 = blockIdx.y * 64;
  const int w = tid >> 6, l = tid & 63;
  const int l15 = l & 15, lq = l >> 4, k8 = lq << 3;
  const int wm = w >> 1, wn = w & 1;
  const int KLEN = KI * DD;
  // pre-swizzled staging source column
  const int stage_col = ((l & 7) ^ (l >> 3)) * 8;
  const int stage_row = l >> 3;

  f32x4 acc[2][4];
#pragma unroll
  for (int m = 0; m < 2; ++m)
#pragma unroll
    for (int n = 0; n < 4; ++n) acc[m][n] = (f32x4){0.f, 0.f, 0.f, 0.f};

  for (int k0 = 0; k0 < KLEN; k0 += 64) {
    __syncthreads();
#pragma unroll
    for (int j = 0; j < 2; ++j) {  // A tile [64][64]
      int row = (w * 2 + j) * 8 + stage_row;
      const f16* g = xt + (size_t)(m0 + row) * KLEN + k0 + stage_col;
      gload_lds16(g, at + (w * 2 + j) * 8 * 64);
    }
#pragma unroll
    for (int j = 0; j < 4; ++j) {  // B tile [128][64]
      int row = (w * 4 + j) * 8 + stage_row;
      const f16* g = mht + (size_t)(n0 + row) * (NK * DD) + kc0 + k0 + stage_col;
      gload_lds16(g, btl + (w * 4 + j) * 8 * 64);
    }
    __syncthreads();
#pragma unroll
    for (int ks = 0; ks < 2; ++ks) {
      f16x8 Bf[4];
#pragma unroll
      for (int n = 0; n < 4; ++n) {
        int lin = (wn * 64 + n * 16 + l15) * 128 + ks * 64 + lq * 16;
        lin ^= (l15 & 7) << 4;
        Bf[n] = *(const f16x8*)((const char*)btl + lin);
      }
#pragma unroll
      for (int m = 0; m < 2; ++m) {
        int lin = (wm * 32 + m * 16 + l15) * 128 + ks * 64 + lq * 16;
        lin ^= (l15 & 7) << 4;
        f16x8 Af = *(const f16x8*)((const char*)at + lin);
#pragma unroll
        for (int n = 0; n < 4; ++n)
          acc[m][n] = __builtin_amdgcn_mfma_f32_16x16x32_f16(Af, Bf[n], acc[m][n], 0, 0, 0);
      }
    }
  }

#pragma unroll
  for (int m = 0; m < 2; ++m) {
    int row = m0 + wm * 32 + m * 16 + lq * 4;
#pragma unroll
    for (int n = 0; n < 4; ++n) {
      int e = n0 + wn * 64 + n * 16 + l15;
      float* dst = out + (size_t)row * DD + e;
#pragma unroll
      for (int r = 0; r < 4; ++r) {
        float v = acc[m][n][r];
        if (beta) v += dst[(size_t)r * DD];
        dst[(size_t)r * DD] = v;
      }
    }
  }
}

extern "C" void kernel_launch(void* const* d_in, const int* in_sizes, int n_in,
                              void* d_out, int out_size, void* d_ws, size_t ws_size,
                              hipStream_t stream) {
  const float* u    = (const float*)d_in[0];  // [4,2048,512]
  const float* ev   = (const float*)d_in[1];  // [24]
  const float* evec = (const float*)d_in[2];  // [2048,24]
  const float* mp   = (const float*)d_in[3];  // [12288,512]
  float* out = (float*)d_out;
  char* ws = (char*)d_ws;

  const size_t UT_OFF   = 0;                       // 8,388,608 B
  const size_t MHT_OFF  = 8388608;                 // 12,582,912 B
  const size_t VREV_OFF = 20971520;                // 24*8*2184*2 = 838,656 B
  const size_t XT_OFF   = 21810176;

  f16* ut    = (f16*)(ws + UT_OFF);
  f16* mht   = (f16*)(ws + MHT_OFF);
  f16* vrev8 = (f16*)(ws + VREV_OFF);
  f16* xt    = (f16*)(ws + XT_OFF);

  // pick largest i-chunk that fits the workspace
  int KI = 1;
  const int cands[8] = {24, 12, 8, 6, 4, 3, 2, 1};
  for (int ci = 0; ci < 8; ++ci) {
    size_t need = XT_OFF + (size_t)cands[ci] * 8388608ull;
    if (need <= ws_size) { KI = cands[ci]; break; }
  }
  const int NC = NK / KI;

  k_vrev8<<<dim3(24, 8), 256, 0, stream>>>(ev, evec, vrev8);
  k_tu<<<dim3(SL / 32, DD / 32, BSZ), dim3(32, 8), 0, stream>>>(u, ut);
  k_tm<<<dim3((NK * DD) / 32, DD / 32), dim3(32, 8), 0, stream>>>(mp, mht);

  for (int c = 0; c < NC; ++c) {
    k_conv<<<dim3(32, KI, BSZ), 256, 0, stream>>>(ut, vrev8, xt, KI, c * KI);
    k_gemm<<<dim3(DD / 128, (BSZ * SL) / 64), 256, 0, stream>>>(
        xt, mht, out, KI, c * KI * DD, c > 0);
  }
}

// Round 3
// 531.551 us; speedup vs baseline: 1.1791x; 1.0274x over previous
//
#include <hip/hip_runtime.h>

typedef _Float16 f16;
typedef _Float16 f16x4 __attribute__((ext_vector_type(4)));
typedef _Float16 f16x8 __attribute__((ext_vector_type(8)));
typedef float    f32x4 __attribute__((ext_vector_type(4)));

#define BSZ 4
#define SL  2048
#define NK  24
#define DD  512
#define VCOPY 2184   // halfs per shifted copy; 1092 dwords == 4 mod 32 -> copies spread over banks

typedef const void GV __attribute__((address_space(1)));
typedef void       LV __attribute__((address_space(3)));

__device__ __forceinline__ void gload_lds16(const void* gp, void* lp) {
  // dest = lp (wave-uniform) + lane*16
  __builtin_amdgcn_global_load_lds((GV*)gp, (LV*)lp, 16, 0, 0);
}

// ---------------- prep: vrev4[i][c][j] = val(j+c), val(p)= p<2048 ? v[2047-p,i]*lam_i^0.25 : 0
__global__ void k_vrev4(const float* __restrict__ eig_vals,
                        const float* __restrict__ eig_vecs,
                        f16* __restrict__ vrev4) {
  int i = blockIdx.x, c = blockIdx.y;  // c in 0..3
  float sc = sqrtf(sqrtf(eig_vals[i]));
  f16* dst = vrev4 + ((size_t)i * 4 + c) * VCOPY;
  for (int j = threadIdx.x; j < VCOPY; j += 256) {
    int p = j + c;
    float v = (p < SL) ? eig_vecs[(size_t)(SL - 1 - p) * NK + i] * sc : 0.f;
    dst[j] = (f16)v;
  }
}

// ---------------- prep: ut[b][d][s] = (f16) u[b][s][d]
__global__ void k_tu(const float* __restrict__ u, f16* __restrict__ ut) {
  __shared__ float tile[32][33];
  int b = blockIdx.z;
  int s0 = blockIdx.x * 32, d0 = blockIdx.y * 32;
  int tx = threadIdx.x, ty = threadIdx.y;
#pragma unroll
  for (int r = 0; r < 4; ++r) {
    int s = s0 + ty * 4 + r;
    tile[ty * 4 + r][tx] = u[((size_t)b * SL + s) * DD + d0 + tx];
  }
  __syncthreads();
#pragma unroll
  for (int r = 0; r < 4; ++r) {
    int d = d0 + ty * 4 + r;
    ut[((size_t)b * DD + d) * SL + s0 + tx] = (f16)tile[tx][ty * 4 + r];
  }
}

// ---------------- prep: mht[e][k] = (f16) m_phi[k][e]   (B^T layout)
__global__ void k_tm(const float* __restrict__ mp, f16* __restrict__ mht) {
  __shared__ float tile[32][33];
  int k0 = blockIdx.x * 32, e0 = blockIdx.y * 32;
  int tx = threadIdx.x, ty = threadIdx.y;
#pragma unroll
  for (int r = 0; r < 4; ++r)
    tile[ty * 4 + r][tx] = mp[(size_t)(k0 + ty * 4 + r) * DD + e0 + tx];
  __syncthreads();
#pragma unroll
  for (int r = 0; r < 4; ++r)
    mht[(size_t)(e0 + ty * 4 + r) * (NK * DD) + k0 + tx] = (f16)tile[tx][ty * 4 + r];
}

// ---------------- phase A: causal Toeplitz conv -> xt[b][t][iL*512+d] (fp16)
// grid: x = 32 (tb 16 x dhalf 2), y = KI, z = b ; 256 threads (4 waves), wave tile 128t x 64d
// bt swizzle: phys = lin ^ ((row&3)<<4); double-buffered with 1-deep prefetch (T3-min)
__global__ __launch_bounds__(256, 2) void k_conv(
    const f16* __restrict__ ut, const f16* __restrict__ vrev4,
    f16* __restrict__ xt, int KI, int ibase) {
  __shared__ f16 vl[4 * VCOPY];      // 17,472 B
  __shared__ f16 bt[2][256 * 32];    // 32,768 B  -> total ~50.2 KB, 3 blocks/CU
  const int tid = threadIdx.x;
  const int tb = 15 - (blockIdx.x >> 1);   // reversed: big K-loops first
  const int dh = blockIdx.x & 1;
  const int iL = blockIdx.y;
  const int i  = ibase + iL;
  const int b  = blockIdx.z;
  const int t0 = tb * 128;

  { // stage 4 shifted copies of vrev (linear 16B copy)
    const uint4* src = (const uint4*)(vrev4 + (size_t)i * (4 * VCOPY));
    uint4* dst = (uint4*)vl;
    for (int p = tid; p < (4 * VCOPY) / 8; p += 256) dst[p] = src[p];
  }

  const int w = tid >> 6, l = tid & 63;
  const int l15 = l & 15, lq = l >> 4, k8 = lq << 3;
  // pre-swizzled global column for B staging (write-side of the involution)
  const int stage_col = ((l & 3) ^ ((l >> 2) & 3)) * 8;
  const int stage_row = l >> 2;

  const f16* utb = ut + (size_t)b * DD * SL;

  auto stage = [&](int buf, int s0) {
#pragma unroll
    for (int j = 0; j < 4; ++j) {
      int row = w * 64 + j * 16 + stage_row;
      const f16* g = utb + (size_t)(dh * 256 + row) * SL + s0 + stage_col;
      gload_lds16(g, &bt[buf][(w * 64 + j * 16) * 32]);
    }
  };

  f32x4 acc[8][4];
#pragma unroll
  for (int m = 0; m < 8; ++m)
#pragma unroll
    for (int n = 0; n < 4; ++n) acc[m][n] = (f32x4){0.f, 0.f, 0.f, 0.f};

  const int nIter = 4 * (tb + 1);
  stage(0, 0);
  __syncthreads();   // drains vmcnt (gload) + lgkm (vl writes), then barrier
  int cur = 0;

  for (int it = 0; it < nIter; ++it) {
    if (it + 1 < nIter) stage(cur ^ 1, (it + 1) * 32);   // prefetch next tile

    f16x8 B[4];
#pragma unroll
    for (int n = 0; n < 4; ++n) {
      int lin = (w * 64 + n * 16 + l15) * 64 + lq * 16;
      lin ^= (l15 & 3) << 4;
      B[n] = *(const f16x8*)((const char*)&bt[cur][0] + lin);
    }

    const int s0 = it * 32;
    const int cbase = 2047 - t0 + s0 + k8;
    __builtin_amdgcn_s_setprio(1);
#pragma unroll
    for (int m = 0; m < 8; ++m) {
      int idx = cbase - (m * 16 + l15);     // vrev index of k-slot j=0 (ascending in j)
      int c = idx & 3, a = idx & ~3;
      const f16* ap = vl + c * VCOPY + a;   // 8B-aligned
      f16x4 lo = *(const f16x4*)ap;
      f16x4 hi = *(const f16x4*)(ap + 4);
      f16x8 A = __builtin_shufflevector(lo, hi, 0, 1, 2, 3, 4, 5, 6, 7);
#pragma unroll
      for (int n = 0; n < 4; ++n)
        acc[m][n] = __builtin_amdgcn_mfma_f32_16x16x32_f16(A, B[n], acc[m][n], 0, 0, 0);
    }
    __builtin_amdgcn_s_setprio(0);

    __syncthreads();   // single barrier/iter: drains prefetch vmcnt, protects dbuf WAR
    cur ^= 1;
  }

  // store xt fp16: D frag: col=lane&15 (d), row=(lane>>4)*4+r (t)
  const size_t rowlen = (size_t)KI * DD;
  const int dbase = dh * 256 + w * 64;
#pragma unroll
  for (int m = 0; m < 8; ++m) {
    int t = t0 + m * 16 + lq * 4;
#pragma unroll
    for (int n = 0; n < 4; ++n) {
      int d = dbase + n * 16 + l15;
      f16* dst = xt + ((size_t)(b * SL + t) * KI + iL) * DD + d;
#pragma unroll
      for (int r = 0; r < 4; ++r)
        dst[(size_t)r * rowlen] = (f16)acc[m][n][r];
    }
  }
}

// ---------------- phase B: out[8192][512] (+)= xt[8192][KI*512] @ mht^T
// BM=64, BN=128, BK=64; grid (4, 128); 256 thr, 4 waves (2m x 2n), wave 32x64
// at/btl swizzle: phys = lin ^ ((row&7)<<4); double-buffered, 1-deep prefetch
__global__ __launch_bounds__(256) void k_gemm(
    const f16* __restrict__ xt, const f16* __restrict__ mht,
    float* __restrict__ out, int KI, int kc0, int beta) {
  __shared__ f16 at[2][64 * 64];      // 16 KB
  __shared__ f16 btl[2][128 * 64];    // 32 KB  -> 48 KB total, 3 blocks/CU
  const int tid = threadIdx.x;
  const int n0 = blockIdx.x * 128;
  const int m0 = blockIdx.y * 64;
  const int w = tid >> 6, l = tid & 63;
  const int l15 = l & 15, lq = l >> 4;
  const int wm = w >> 1, wn = w & 1;
  const int KLEN = KI * DD;
  // pre-swizzled staging source column
  const int stage_col = ((l & 7) ^ (l >> 3)) * 8;
  const int stage_row = l >> 3;

  auto stage = [&](int buf, int k0) {
#pragma unroll
    for (int j = 0; j < 2; ++j) {  // A tile [64][64]
      int row = (w * 2 + j) * 8 + stage_row;
      const f16* g = xt + (size_t)(m0 + row) * KLEN + k0 + stage_col;
      gload_lds16(g, &at[buf][(w * 2 + j) * 8 * 64]);
    }
#pragma unroll
    for (int j = 0; j < 4; ++j) {  // B tile [128][64]
      int row = (w * 4 + j) * 8 + stage_row;
      const f16* g = mht + (size_t)(n0 + row) * (NK * DD) + kc0 + k0 + stage_col;
      gload_lds16(g, &btl[buf][(w * 4 + j) * 8 * 64]);
    }
  };

  f32x4 acc[2][4];
#pragma unroll
  for (int m = 0; m < 2; ++m)
#pragma unroll
    for (int n = 0; n < 4; ++n) acc[m][n] = (f32x4){0.f, 0.f, 0.f, 0.f};

  const int nIter = KLEN / 64;
  stage(0, 0);
  __syncthreads();
  int cur = 0;

  for (int it = 0; it < nIter; ++it) {
    if (it + 1 < nIter) stage(cur ^ 1, (it + 1) * 64);

#pragma unroll
    for (int ks = 0; ks < 2; ++ks) {
      f16x8 Bf[4];
#pragma unroll
      for (int n = 0; n < 4; ++n) {
        int lin = (wn * 64 + n * 16 + l15) * 128 + ks * 64 + lq * 16;
        lin ^= (l15 & 7) << 4;
        Bf[n] = *(const f16x8*)((const char*)&btl[cur][0] + lin);
      }
#pragma unroll
      for (int m = 0; m < 2; ++m) {
        int lin = (wm * 32 + m * 16 + l15) * 128 + ks * 64 + lq * 16;
        lin ^= (l15 & 7) << 4;
        f16x8 Af = *(const f16x8*)((const char*)&at[cur][0] + lin);
#pragma unroll
        for (int n = 0; n < 4; ++n)
          acc[m][n] = __builtin_amdgcn_mfma_f32_16x16x32_f16(Af, Bf[n], acc[m][n], 0, 0, 0);
      }
    }

    __syncthreads();
    cur ^= 1;
  }

#pragma unroll
  for (int m = 0; m < 2; ++m) {
    int row = m0 + wm * 32 + m * 16 + lq * 4;
#pragma unroll
    for (int n = 0; n < 4; ++n) {
      int e = n0 + wn * 64 + n * 16 + l15;
      float* dst = out + (size_t)row * DD + e;
#pragma unroll
      for (int r = 0; r < 4; ++r) {
        float v = acc[m][n][r];
        if (beta) v += dst[(size_t)r * DD];
        dst[(size_t)r * DD] = v;
      }
    }
  }
}

extern "C" void kernel_launch(void* const* d_in, const int* in_sizes, int n_in,
                              void* d_out, int out_size, void* d_ws, size_t ws_size,
                              hipStream_t stream) {
  const float* u    = (const float*)d_in[0];  // [4,2048,512]
  const float* ev   = (const float*)d_in[1];  // [24]
  const float* evec = (const float*)d_in[2];  // [2048,24]
  const float* mp   = (const float*)d_in[3];  // [12288,512]
  float* out = (float*)d_out;
  char* ws = (char*)d_ws;

  const size_t UT_OFF   = 0;                       // 8,388,608 B
  const size_t MHT_OFF  = 8388608;                 // 12,582,912 B
  const size_t VREV_OFF = 20971520;                // 24*4*2184*2 = 419,328 B
  const size_t XT_OFF   = 21390848;

  f16* ut    = (f16*)(ws + UT_OFF);
  f16* mht   = (f16*)(ws + MHT_OFF);
  f16* vrev4 = (f16*)(ws + VREV_OFF);
  f16* xt    = (f16*)(ws + XT_OFF);

  // pick largest i-chunk that fits the workspace
  int KI = 1;
  const int cands[8] = {24, 12, 8, 6, 4, 3, 2, 1};
  for (int ci = 0; ci < 8; ++ci) {
    size_t need = XT_OFF + (size_t)cands[ci] * 8388608ull;
    if (need <= ws_size) { KI = cands[ci]; break; }
  }
  const int NC = NK / KI;

  k_vrev4<<<dim3(24, 4), 256, 0, stream>>>(ev, evec, vrev4);
  k_tu<<<dim3(SL / 32, DD / 32, BSZ), dim3(32, 8), 0, stream>>>(u, ut);
  k_tm<<<dim3((NK * DD) / 32, DD / 32), dim3(32, 8), 0, stream>>>(mp, mht);

  for (int c = 0; c < NC; ++c) {
    k_conv<<<dim3(32, KI, BSZ), 256, 0, stream>>>(ut, vrev4, xt, KI, c * KI);
    k_gemm<<<dim3(DD / 128, (BSZ * SL) / 64), 256, 0, stream>>>(
        xt, mht, out, KI, c * KI * DD, c > 0);
  }
}